// Round 16
// baseline (351.908 us; speedup 1.0000x reference)
//
#include <hip/hip_runtime.h>
#include <hip/hip_bf16.h>
#include <math.h>

// Round 26-retry: identical to R26 (prior bench died with UnresponsiveContainer
// before launch — infra flake; code re-audited: no divergent barriers, no OOB,
// staging liveness correct). Occupancy via two-round view staging:
// stage views in 2 rounds of 3 through xt[3] (24.6KB); gacc covers all 6
// views (loads all in flight) so Q/gq unchanged; round 1 re-reads v3-5
// (L2-hot); V accumulates RAW e (divide at end); fc: v0-2 from fp32 re-read,
// v3-5 from staged xt; full x-bar tile (8KB, no barrier dance).
// LDS 37,888 B -> 4 blocks/CU (+33% TLP), launch_bounds(256,4).
// conv3 v3 / setup / pack / launcher: byte-identical to R25 (142.3us).
// B=4 N=6 C=128 H=W=128, HEADS=4 HD=32 MID=32.

#define BB   4
#define NV   6
#define CH   128
#define HGT  128
#define WID  128
#define MIDD 32
#define HWP  (HGT*WID)
#define TP   32

#define SWZ(pix) ((((pix) & 15) << 3) ^ (((pix) & 24) << 1))

typedef __attribute__((ext_vector_type(8))) short bf16x8;
typedef __attribute__((ext_vector_type(4))) float f32x4;
typedef __attribute__((ext_vector_type(2))) unsigned int u32x2;

union U8 { bf16x8 v; unsigned u[4]; };

__device__ __forceinline__ ushort f2bf(float f) {
    union { __hip_bfloat16 h; ushort u; } v;
    v.h = __float2bfloat16(f);
    return v.u;
}
__device__ __forceinline__ float bf2f(ushort u) {
    return __uint_as_float(((unsigned)u) << 16);
}
__device__ __forceinline__ unsigned cvt_pk_bf16(float lo, float hi) {
    unsigned r;
    asm("v_cvt_pk_bf16_f32 %0, %1, %2" : "=v"(r) : "v"(lo), "v"(hi));
    return r;
}

// ---------------- setup: rel_bias, gate ----------------
__global__ void fusion_setup(const float* __restrict__ snr, const float* __restrict__ vr,
                             const float* __restrict__ Wg, const float* __restrict__ bg,
                             const float* __restrict__ Wr1, const float* __restrict__ br1,
                             const float* __restrict__ Wr2, const float* __restrict__ br2,
                             float* __restrict__ relb, float* __restrict__ gate)
{
    int tid = blockIdx.x * blockDim.x + threadIdx.x;
    if (tid < BB*CH) {
        int b = tid >> 7, c = tid & 127;
        float s = snr[b] * 0.05f;
        s = fminf(fmaxf(s, -1.5f), 1.5f);
        float z = s * Wg[c] + bg[c];
        gate[tid] = 1.0f / (1.0f + __expf(-z));
    }
    if (tid < BB*NV) {
        int b = tid / NV, n = tid % NV;
        float v0 = vr[(b*NV+n)*3+0], v1 = vr[(b*NV+n)*3+1], v2 = vr[(b*NV+n)*3+2];
        float acc = br2[0];
        for (int j = 0; j < MIDD; ++j) {
            float h = Wr1[j*3+0]*v0 + Wr1[j*3+1]*v1 + Wr1[j*3+2]*v2 + br1[j];
            acc += Wr2[j] * fmaxf(h, 0.0f);
        }
        relb[tid] = acc;
    }
}

// ---------------- weight frag-packing ----------------
__global__ void pack_weights(const float* __restrict__ Wq, const float* __restrict__ Wk,
                             const float* __restrict__ Wv, const float* __restrict__ Wo1,
                             const float* __restrict__ Wc1, const float* __restrict__ Wo2,
                             ushort* __restrict__ wqp, ushort* __restrict__ wkp,
                             ushort* __restrict__ wvp, ushort* __restrict__ wo1p,
                             ushort* __restrict__ wc1p, ushort* __restrict__ wo2p)
{
    int tid = blockIdx.x * 256 + threadIdx.x;
    if (tid >= 27136) return;
    if (tid < 8192) {
        int m = tid >> 11;
        int local = tid & 2047;
        const float* src = (m == 0) ? Wq : (m == 1) ? Wk : (m == 2) ? Wv : Wo1;
        ushort* dst = (m == 0) ? wqp : (m == 1) ? wkp : (m == 2) ? wvp : wo1p;
        int ks = local >> 9, rem = local & 511;
        int nf = rem >> 6, lane = rem & 63;
        int o = nf*16 + (lane & 15);
        int i0 = ks*32 + ((lane >> 4) << 3);
        const float* s = src + o*CH + i0;
        ushort* d = dst + local*8;
#pragma unroll
        for (int j = 0; j < 8; ++j) d[j] = f2bf(s[j]);
    } else if (tid < 8704) {
        int local = tid - 8192;
        int ks = local >> 7, rem = local & 127;
        int nf = rem >> 6, lane = rem & 63;
        int o = nf*16 + (lane & 15);
        int i0 = ks*32 + ((lane >> 4) << 3);
        const float* s = Wc1 + o*CH + i0;
        ushort* d = wc1p + local*8;
#pragma unroll
        for (int j = 0; j < 8; ++j) d[j] = f2bf(s[j]);
    } else {
        int l2 = tid - 8704;
        int lane = l2 & 63;
        int rest = l2 >> 6;
        int nf = rest & 7;
        int kst = rest >> 3;
        int ks = kst & 3;
        int tap = kst >> 2;
        int co = nf*16 + (lane & 15);
        int ci0 = ks*32 + ((lane >> 4) << 3);
        ushort* d = wo2p + l2*8;
#pragma unroll
        for (int j = 0; j < 8; ++j) d[j] = f2bf(Wo2[(co*CH + ci0 + j)*9 + tap]);
    }
}

// ---------------- MFMA helpers ----------------
__device__ __forceinline__ bf16x8 ldsA(const ushort* tile, int lane, int mf, int ks) {
    int pix = mf*16 + (lane & 15);
    int idx = (pix*128 + ks*32 + ((lane >> 4) << 3)) ^ SWZ(pix);
    return *(const bf16x8*)(tile + idx);
}
__device__ __forceinline__ bf16x8 ldB(const ushort* pack, int lane, int ks, int nf, int NF) {
    return *(const bf16x8*)(pack + (((ks*NF + nf)*64) + lane)*8);
}

// conf sub-computation for one view (wave-uniform call)
__device__ __forceinline__ void conf_one(const ushort* xtile, int n, int lane, int rg,
                                         const ushort* __restrict__ wc1p,
                                         const float* __restrict__ bc1,
                                         const float* __restrict__ Wc2,
                                         float (*lpart)[TP])
{
    bf16x8 xA[2][4];
#pragma unroll
    for (int mf = 0; mf < 2; ++mf)
#pragma unroll
        for (int ks = 0; ks < 4; ++ks) xA[mf][ks] = ldsA(xtile, lane, mf, ks);
    f32x4 cf[2][2];
#pragma unroll
    for (int mf = 0; mf < 2; ++mf)
#pragma unroll
        for (int nfc = 0; nfc < 2; ++nfc) cf[mf][nfc] = (f32x4){0.f,0.f,0.f,0.f};
#pragma unroll
    for (int nfc = 0; nfc < 2; ++nfc) {
#pragma unroll
        for (int ks = 0; ks < 4; ++ks) {
            bf16x8 bb = ldB(wc1p, lane, ks, nfc, 2);
#pragma unroll
            for (int mf = 0; mf < 2; ++mf)
                cf[mf][nfc] = __builtin_amdgcn_mfma_f32_16x16x32_bf16(bb, xA[mf][ks], cf[mf][nfc], 0, 0, 0);
        }
    }
    const f32x4 bc1T0 = *(const f32x4*)(bc1 + rg),  bc1T1 = *(const f32x4*)(bc1 + 16 + rg);
    const f32x4 wc2T0 = *(const f32x4*)(Wc2 + rg),  wc2T1 = *(const f32x4*)(Wc2 + 16 + rg);
#pragma unroll
    for (int mf = 0; mf < 2; ++mf) {
        float pl = 0.f;
#pragma unroll
        for (int r = 0; r < 4; ++r) {
            pl += fmaxf(cf[mf][0][r] + bc1T0[r], 0.f) * wc2T0[r];
            pl += fmaxf(cf[mf][1][r] + bc1T1[r], 0.f) * wc2T1[r];
        }
        pl += __shfl_xor(pl, 16, 64);
        pl += __shfl_xor(pl, 32, 64);
        if (lane < 16) lpart[n][mf*16 + lane] = pl;
    }
}

// ---------------- fusion_attn: per (b, 32-pix tile), 2-round staging ----------------
__global__ __launch_bounds__(256, 4) void fusion_attn(
    const float* __restrict__ bev,
    const ushort* __restrict__ wqp, const ushort* __restrict__ wkp,
    const ushort* __restrict__ wvp, const ushort* __restrict__ wo1p,
    const ushort* __restrict__ wc1p,
    const float* __restrict__ bq, const float* __restrict__ bk,
    const float* __restrict__ bv, const float* __restrict__ bo1,
    const float* __restrict__ bc1, const float* __restrict__ bc2,
    const float* __restrict__ Wc2, const float* __restrict__ relb,
    ushort* __restrict__ gq_bf, ushort* __restrict__ t_bf, ushort* __restrict__ fc_bf,
    float* __restrict__ attn_o, float* __restrict__ conf_o)
{
    __shared__ ushort xt[3][TP*128];    // swizzled [pix][c] bf16; round 0: v0-2, round 1: v3-5
    __shared__ ushort gqh[TP*128];      // x-bar full tile (8KB)
    __shared__ float  scat[NV][4][TP];  // raw e per (view, head, pix)
    __shared__ float  dnm[4][TP];       // 1/denom per (head, pix)
    __shared__ float  lpart[NV][TP];
    __shared__ float  cfw[NV][TP];
    // LDS total: 24576 + 8192 + 3072 + 512 + 768 + 768 = 37888 -> 4 blocks/CU

    const int t = threadIdx.x, lane = t & 63, w = t >> 6;
    // bijective XCD swizzle: 2048 blocks = 8 XCDs x 256 contiguous tiles.
    const int vb = ((blockIdx.x & 7) << 8) | (blockIdx.x >> 3);
    const int b = vb >> 9;
    const int pix0 = (vb & 511) * TP;

    // ---- Phase A: all 24 loads in flight; stage v0-2; gacc over all 6 ----
    const int pixg = (t & 3) * 8;
    const int c0   = (t >> 2) * 2;
    const float* sb = bev + (((size_t)b*NV*CH + c0)*HWP + pix0 + pixg);
    const size_t vstep = (size_t)CH*HWP;
    float gacc[16];
#pragma unroll
    for (int i = 0; i < 16; ++i) gacc[i] = 0.f;
    {
        float4 L[NV][4];
#pragma unroll
        for (int j = 0; j < NV; ++j) {
            const float* s1 = sb + (size_t)j*vstep;
            L[j][0] = *(const float4*)(s1);
            L[j][1] = *(const float4*)(s1 + 4);
            L[j][2] = *(const float4*)(s1 + HWP);
            L[j][3] = *(const float4*)(s1 + HWP + 4);
        }
#pragma unroll
        for (int n = 0; n < NV; ++n) {
            float4 a0 = L[n][0], a1 = L[n][1], b0 = L[n][2], b1 = L[n][3];
            float r0[8] = {a0.x,a0.y,a0.z,a0.w, a1.x,a1.y,a1.z,a1.w};
            float r1[8] = {b0.x,b0.y,b0.z,b0.w, b1.x,b1.y,b1.z,b1.w};
#pragma unroll
            for (int p = 0; p < 8; ++p) {
                int pix = pixg + p;
                if (n < 3) {
                    unsigned pk = cvt_pk_bf16(r0[p], r1[p]);
                    *(unsigned*)(&xt[n][(pix*128 + c0) ^ SWZ(pix)]) = pk;
                }
                gacc[p]   += r0[p];
                gacc[8+p] += r1[p];
            }
        }
    }
    {
        U8 g0, g1;
#pragma unroll
        for (int p = 0; p < 4; ++p) {
            g0.u[p] = cvt_pk_bf16(gacc[2*p]   * (1.0f/6.0f), gacc[2*p+1] * (1.0f/6.0f));
            g1.u[p] = cvt_pk_bf16(gacc[8+2*p] * (1.0f/6.0f), gacc[9+2*p] * (1.0f/6.0f));
        }
        ushort* gd = gq_bf + ((size_t)(b*CH + c0)*HWP + pix0 + pixg);
        *(bf16x8*)(gd)       = g0.v;
        *(bf16x8*)(gd + HWP) = g1.v;
    }
    // full x-bar tile
#pragma unroll
    for (int p = 0; p < 8; ++p) {
        int pix = pixg + p;
        unsigned pk = cvt_pk_bf16(gacc[p]*(1.0f/6.0f), gacc[8+p]*(1.0f/6.0f));
        *(unsigned*)(&gqh[(pix*128 + c0) ^ SWZ(pix)]) = pk;
    }
    __syncthreads();   // B1

    const int cl0 = (lane & 15);
    const int rg  = (lane >> 4) << 2;

    // ---- Q = Wq · x-bar (32 MFMAs over the full tile) + bias ----
    f32x4 qf[2][2];
#pragma unroll
    for (int mf = 0; mf < 2; ++mf)
#pragma unroll
        for (int nfl = 0; nfl < 2; ++nfl) qf[mf][nfl] = (f32x4){0.f,0.f,0.f,0.f};
#pragma unroll
    for (int mf = 0; mf < 2; ++mf) {
        bf16x8 xg[4];
#pragma unroll
        for (int ks = 0; ks < 4; ++ks) xg[ks] = ldsA(gqh, lane, mf, ks);
#pragma unroll
        for (int nfl = 0; nfl < 2; ++nfl)
#pragma unroll
            for (int ks = 0; ks < 4; ++ks)
                qf[mf][nfl] = __builtin_amdgcn_mfma_f32_16x16x32_bf16(
                    ldB(wqp, lane, ks, 2*w + nfl, 8), xg[ks], qf[mf][nfl], 0, 0, 0);
    }
    {
        const f32x4 bqT0 = *(const f32x4*)(bq + w*32 + rg), bqT1 = *(const f32x4*)(bq + w*32 + 16 + rg);
#pragma unroll
        for (int mf = 0; mf < 2; ++mf)
#pragma unroll
            for (int r = 0; r < 4; ++r) {
                qf[mf][0][r] = qf[mf][0][r] + bqT0[r];
                qf[mf][1][r] = qf[mf][1][r] + bqT1[r];
            }
    }
    float sb2[2];
    {
        const f32x4 bkT0 = *(const f32x4*)(bk + w*32 + rg), bkT1 = *(const f32x4*)(bk + w*32 + 16 + rg);
#pragma unroll
        for (int mf = 0; mf < 2; ++mf) {
            float v = 0.f;
#pragma unroll
            for (int r = 0; r < 4; ++r) {
                v += qf[mf][0][r]*bkT0[r];
                v += qf[mf][1][r]*bkT1[r];
            }
            sb2[mf] = v;
        }
    }

    // ---- Round 0: views 0-2 (conf, K, V-raw) ----
    if (w < 3) conf_one(xt[w], w, lane, rg, wc1p, bc1, Wc2, lpart);

    float denom[2] = {0.f, 0.f};
    f32x4 ff[2][2];
#pragma unroll
    for (int mf = 0; mf < 2; ++mf)
#pragma unroll
        for (int nfl = 0; nfl < 2; ++nfl) ff[mf][nfl] = (f32x4){0.f,0.f,0.f,0.f};
#pragma unroll
    for (int n = 0; n < 3; ++n) {
        bf16x8 xA[2][4];
#pragma unroll
        for (int mf = 0; mf < 2; ++mf)
#pragma unroll
            for (int ks = 0; ks < 4; ++ks) xA[mf][ks] = ldsA(xt[n], lane, mf, ks);
        f32x4 kf[2][2];
#pragma unroll
        for (int mf = 0; mf < 2; ++mf)
#pragma unroll
            for (int nfl = 0; nfl < 2; ++nfl) kf[mf][nfl] = (f32x4){0.f,0.f,0.f,0.f};
#pragma unroll
        for (int nfl = 0; nfl < 2; ++nfl)
#pragma unroll
            for (int ks = 0; ks < 4; ++ks) {
                bf16x8 bb = ldB(wkp, lane, ks, 2*w + nfl, 8);
#pragma unroll
                for (int mf = 0; mf < 2; ++mf)
                    kf[mf][nfl] = __builtin_amdgcn_mfma_f32_16x16x32_bf16(bb, xA[mf][ks], kf[mf][nfl], 0, 0, 0);
            }
#pragma unroll
        for (int mf = 0; mf < 2; ++mf) {
            float s = sb2[mf];
#pragma unroll
            for (int r = 0; r < 4; ++r) {
                s += qf[mf][0][r]*kf[mf][0][r];
                s += qf[mf][1][r]*kf[mf][1][r];
            }
            s += __shfl_xor(s, 16, 64);
            s += __shfl_xor(s, 32, 64);
            float e = __expf(s * 0.17677669529663687f);
            denom[mf] += e;
            if (lane < 16) scat[n][w][mf*16 + lane] = e;
        }
        f32x4 vv[2][2];
#pragma unroll
        for (int mf = 0; mf < 2; ++mf)
#pragma unroll
            for (int nfl = 0; nfl < 2; ++nfl) vv[mf][nfl] = (f32x4){0.f,0.f,0.f,0.f};
#pragma unroll
        for (int nfl = 0; nfl < 2; ++nfl)
#pragma unroll
            for (int ks = 0; ks < 4; ++ks) {
                bf16x8 bb = ldB(wvp, lane, ks, 2*w + nfl, 8);
#pragma unroll
                for (int mf = 0; mf < 2; ++mf)
                    vv[mf][nfl] = __builtin_amdgcn_mfma_f32_16x16x32_bf16(bb, xA[mf][ks], vv[mf][nfl], 0, 0, 0);
            }
        float a0 = scat[n][w][cl0];        // raw e (normalize at end)
        float a1 = scat[n][w][16 + cl0];
#pragma unroll
        for (int r = 0; r < 4; ++r) {
            ff[0][0][r] += a0 * vv[0][0][r];
            ff[0][1][r] += a0 * vv[0][1][r];
            ff[1][0][r] += a1 * vv[1][0][r];
            ff[1][1][r] += a1 * vv[1][1][r];
        }
    }
    __syncthreads();   // B2a: xt v0-2 dead

    // ---- Round 1 stage: re-read v3-5 (L2-hot) -> xt slots 0-2 ----
    {
        float4 M[3][4];
#pragma unroll
        for (int j = 0; j < 3; ++j) {
            const float* s1 = sb + (size_t)(j+3)*vstep;
            M[j][0] = *(const float4*)(s1);
            M[j][1] = *(const float4*)(s1 + 4);
            M[j][2] = *(const float4*)(s1 + HWP);
            M[j][3] = *(const float4*)(s1 + HWP + 4);
        }
#pragma unroll
        for (int j = 0; j < 3; ++j) {
            float4 a0 = M[j][0], a1 = M[j][1], b0 = M[j][2], b1 = M[j][3];
            float r0[8] = {a0.x,a0.y,a0.z,a0.w, a1.x,a1.y,a1.z,a1.w};
            float r1[8] = {b0.x,b0.y,b0.z,b0.w, b1.x,b1.y,b1.z,b1.w};
#pragma unroll
            for (int p = 0; p < 8; ++p) {
                int pix = pixg + p;
                unsigned pk = cvt_pk_bf16(r0[p], r1[p]);
                *(unsigned*)(&xt[j][(pix*128 + c0) ^ SWZ(pix)]) = pk;
            }
        }
    }
    __syncthreads();   // B2b: v3-5 staged

    // ---- Round 1: views 3-5 (conf, K, V-raw) ----
    if (w == 3) conf_one(xt[0], 3, lane, rg, wc1p, bc1, Wc2, lpart);
    if (w < 2)  conf_one(xt[w + 1], w + 4, lane, rg, wc1p, bc1, Wc2, lpart);

#pragma unroll
    for (int n = 3; n < NV; ++n) {
        bf16x8 xA[2][4];
#pragma unroll
        for (int mf = 0; mf < 2; ++mf)
#pragma unroll
            for (int ks = 0; ks < 4; ++ks) xA[mf][ks] = ldsA(xt[n-3], lane, mf, ks);
        f32x4 kf[2][2];
#pragma unroll
        for (int mf = 0; mf < 2; ++mf)
#pragma unroll
            for (int nfl = 0; nfl < 2; ++nfl) kf[mf][nfl] = (f32x4){0.f,0.f,0.f,0.f};
#pragma unroll
        for (int nfl = 0; nfl < 2; ++nfl)
#pragma unroll
            for (int ks = 0; ks < 4; ++ks) {
                bf16x8 bb = ldB(wkp, lane, ks, 2*w + nfl, 8);
#pragma unroll
                for (int mf = 0; mf < 2; ++mf)
                    kf[mf][nfl] = __builtin_amdgcn_mfma_f32_16x16x32_bf16(bb, xA[mf][ks], kf[mf][nfl], 0, 0, 0);
            }
#pragma unroll
        for (int mf = 0; mf < 2; ++mf) {
            float s = sb2[mf];
#pragma unroll
            for (int r = 0; r < 4; ++r) {
                s += qf[mf][0][r]*kf[mf][0][r];
                s += qf[mf][1][r]*kf[mf][1][r];
            }
            s += __shfl_xor(s, 16, 64);
            s += __shfl_xor(s, 32, 64);
            float e = __expf(s * 0.17677669529663687f);
            denom[mf] += e;
            if (lane < 16) scat[n][w][mf*16 + lane] = e;
        }
        f32x4 vv[2][2];
#pragma unroll
        for (int mf = 0; mf < 2; ++mf)
#pragma unroll
            for (int nfl = 0; nfl < 2; ++nfl) vv[mf][nfl] = (f32x4){0.f,0.f,0.f,0.f};
#pragma unroll
        for (int nfl = 0; nfl < 2; ++nfl)
#pragma unroll
            for (int ks = 0; ks < 4; ++ks) {
                bf16x8 bb = ldB(wvp, lane, ks, 2*w + nfl, 8);
#pragma unroll
                for (int mf = 0; mf < 2; ++mf)
                    vv[mf][nfl] = __builtin_amdgcn_mfma_f32_16x16x32_bf16(bb, xA[mf][ks], vv[mf][nfl], 0, 0, 0);
            }
        float a0 = scat[n][w][cl0];
        float a1 = scat[n][w][16 + cl0];
#pragma unroll
        for (int r = 0; r < 4; ++r) {
            ff[0][0][r] += a0 * vv[0][0][r];
            ff[0][1][r] += a0 * vv[0][1][r];
            ff[1][0][r] += a1 * vv[1][0][r];
            ff[1][1][r] += a1 * vv[1][1][r];
        }
    }
    const float inv0 = 1.0f/denom[0], inv1 = 1.0f/denom[1];
    if (lane < 32) dnm[w][lane] = (lane & 16) ? inv1 : inv0;
    {
        const f32x4 bvT0 = *(const f32x4*)(bv + w*32 + rg), bvT1 = *(const f32x4*)(bv + w*32 + 16 + rg);
#pragma unroll
        for (int r = 0; r < 4; ++r) {
            ff[0][0][r] = ff[0][0][r]*inv0 + bvT0[r];
            ff[0][1][r] = ff[0][1][r]*inv0 + bvT1[r];
            ff[1][0][r] = ff[1][0][r]*inv1 + bvT0[r];
            ff[1][1][r] = ff[1][1][r]*inv1 + bvT1[r];
        }
    }
    __syncthreads();   // B2

    // ---- conf softmax (t<32) || attn_o mean (t<192) ----
    if (t < 32) {
        int pix = t;
        float bc2v = bc2[0];
        float lg[NV];
#pragma unroll
        for (int n = 0; n < NV; ++n)
            lg[n] = lpart[n][pix] + bc2v + relb[b*NV + n];
        float mx = fmaxf(fmaxf(fmaxf(lg[0],lg[1]),fmaxf(lg[2],lg[3])),fmaxf(lg[4],lg[5]));
        float e[NV], sum = 0.f;
#pragma unroll
        for (int n = 0; n < NV; ++n) { e[n] = __expf(lg[n]-mx); sum += e[n]; }
        float inv = 1.0f/sum;
#pragma unroll
        for (int n = 0; n < NV; ++n) {
            float wv = e[n]*inv;
            cfw[n][pix] = wv;
            conf_o[(b*NV + n)*HWP + pix0 + pix] = wv;
        }
    }
    if (t < 192) {
        int n = t >> 5, pix = t & 31;
        float am = 0.25f*(scat[n][0][pix]*dnm[0][pix] + scat[n][1][pix]*dnm[1][pix]
                        + scat[n][2][pix]*dnm[2][pix] + scat[n][3][pix]*dnm[3][pix]);
        attn_o[(b*NV + n)*HWP + pix0 + pix] = am;
    }
    __syncthreads();   // B3

    // ---- fc: v0-2 from fp32 re-read (L2/L3-hot), v3-5 from staged xt ----
    {
        float fcv[16];
#pragma unroll
        for (int i = 0; i < 16; ++i) fcv[i] = 0.f;
        {
            float4 G[3][4];
#pragma unroll
            for (int j = 0; j < 3; ++j) {
                const float* s1 = sb + (size_t)j*vstep;
                G[j][0] = *(const float4*)(s1);
                G[j][1] = *(const float4*)(s1 + 4);
                G[j][2] = *(const float4*)(s1 + HWP);
                G[j][3] = *(const float4*)(s1 + HWP + 4);
            }
#pragma unroll
            for (int n = 0; n < 3; ++n) {
                float4 a0 = G[n][0], a1 = G[n][1], b0 = G[n][2], b1 = G[n][3];
                float r0[8] = {a0.x,a0.y,a0.z,a0.w, a1.x,a1.y,a1.z,a1.w};
                float r1[8] = {b0.x,b0.y,b0.z,b0.w, b1.x,b1.y,b1.z,b1.w};
#pragma unroll
                for (int p = 0; p < 8; ++p) {
                    float cwv = cfw[n][pixg + p];
                    fcv[p]   += cwv * r0[p];
                    fcv[8+p] += cwv * r1[p];
                }
            }
        }
#pragma unroll
        for (int n = 3; n < NV; ++n) {
#pragma unroll
            for (int p = 0; p < 8; ++p) {
                int pix = pixg + p;
                float cwv = cfw[n][pix];
                unsigned pk = *(const unsigned*)(&xt[n-3][(pix*128 + c0) ^ SWZ(pix)]);
                fcv[p]   += cwv * bf2f((ushort)(pk & 0xffffu));
                fcv[8+p] += cwv * bf2f((ushort)(pk >> 16));
            }
        }
        U8 f0, f1;
#pragma unroll
        for (int p = 0; p < 4; ++p) {
            f0.u[p] = cvt_pk_bf16(fcv[2*p],   fcv[2*p+1]);
            f1.u[p] = cvt_pk_bf16(fcv[8+2*p], fcv[9+2*p]);
        }
        ushort* fd = fc_bf + ((size_t)(b*CH + c0)*HWP + pix0 + pixg);
        *(bf16x8*)(fd)       = f0.v;
        *(bf16x8*)(fd + HWP) = f1.v;
    }
    __syncthreads();   // B4 (fc's xt reads done before overwrite)

    // ---- fused frags -> xt[0] (swizzled), 4 x b64 writes ----
    {
        ushort* xt0 = &xt[0][0];
#pragma unroll
        for (int mf = 0; mf < 2; ++mf)
#pragma unroll
            for (int nfl = 0; nfl < 2; ++nfl) {
                int pix = mf*16 + cl0;
                int c   = w*32 + nfl*16 + rg;
                unsigned lo = cvt_pk_bf16(ff[mf][nfl][0], ff[mf][nfl][1]);
                unsigned hi = cvt_pk_bf16(ff[mf][nfl][2], ff[mf][nfl][3]);
                *(u32x2*)(&xt0[(pix*128 + c) ^ SWZ(pix)]) = (u32x2){lo, hi};
            }
    }
    __syncthreads();   // B5

    // ---- Phase F: t = relu(Wo1 @ fused + bo1) -> t_bf NHWC bf16 ----
    {
        bf16x8 aA[2][4];
#pragma unroll
        for (int mf = 0; mf < 2; ++mf)
#pragma unroll
            for (int ks = 0; ks < 4; ++ks) aA[mf][ks] = ldsA(&xt[0][0], lane, mf, ks);
        f32x4 tf[2][2];
#pragma unroll
        for (int mf = 0; mf < 2; ++mf)
#pragma unroll
            for (int nfl = 0; nfl < 2; ++nfl) tf[mf][nfl] = (f32x4){0.f,0.f,0.f,0.f};
#pragma unroll
        for (int nfl = 0; nfl < 2; ++nfl) {
            int nf = 2*w + nfl;
#pragma unroll
            for (int ks = 0; ks < 4; ++ks) {
                bf16x8 bb = ldB(wo1p, lane, ks, nf, 8);
#pragma unroll
                for (int mf = 0; mf < 2; ++mf)
                    tf[mf][nfl] = __builtin_amdgcn_mfma_f32_16x16x32_bf16(aA[mf][ks], bb, tf[mf][nfl], 0, 0, 0);
            }
        }
        const float bov0 = bo1[w*32 + cl0], bov1 = bo1[w*32 + 16 + cl0];
#pragma unroll
        for (int mf = 0; mf < 2; ++mf)
#pragma unroll
            for (int nfl = 0; nfl < 2; ++nfl)
#pragma unroll
                for (int r = 0; r < 4; ++r) {
                    int pix = mf*16 + rg + r;
                    int c   = w*32 + nfl*16 + cl0;
                    float bo_ = nfl ? bov1 : bov0;
                    t_bf[(size_t)(b*HWP + pix0 + pix)*128 + c] = f2bf(fmaxf(tf[mf][nfl][r] + bo_, 0.f));
                }
    }
}

// ---------------- conv3x3 v3: 8x32 tiles, full-line out writes, channel-split ----------------
__global__ __launch_bounds__(256, 2) void fusion_conv3(
    const ushort* __restrict__ t_bf, const ushort* __restrict__ gq_bf,
    const ushort* __restrict__ fc_bf, const ushort* __restrict__ wo2p,
    const float* __restrict__ bo2, const float* __restrict__ gate,
    float* __restrict__ out)
{
    __shared__ ushort halo[10*34*64];   // 43520 B; reused as fbuf in epilogue

    const int t = threadIdx.x, lane = t & 63, w = t >> 6;
    const int vbk = ((blockIdx.x & 7) << 6) | (blockIdx.x >> 3);
    const int cg   = vbk & 1;
    const int tile = (vbk >> 1) & 63;
    const int b    = vbk >> 7;
    const int h0 = (tile >> 2) * 8;
    const int w0 = (tile & 3) * 32;

    const int c8   = (t & 7) * 8;
    const int cell0 = t >> 3;

    for (int i = cell0; i < 340; i += 32) {
        int r = i / 34, cc = i - r*34;
        int hs = h0 - 1 + r, wsr = w0 - 1 + cc;
        bf16x8 v = (bf16x8){0,0,0,0,0,0,0,0};
        if ((unsigned)hs < (unsigned)HGT && (unsigned)wsr < (unsigned)WID)
            v = *(const bf16x8*)(t_bf + ((size_t)(b*HWP + hs*WID + wsr)*128 + c8));
        *(bf16x8*)(&halo[(i*64 + c8) ^ ((cc & 7) << 3)]) = v;
    }
    bf16x8 stg[11];
#pragma unroll
    for (int j = 0; j < 11; ++j) {
        int i = cell0 + 32*j;
        if (i < 340) {
            int r = i / 34, cc = i - r*34;
            int hs = h0 - 1 + r, wsr = w0 - 1 + cc;
            bf16x8 v = (bf16x8){0,0,0,0,0,0,0,0};
            if ((unsigned)hs < (unsigned)HGT && (unsigned)wsr < (unsigned)WID)
                v = *(const bf16x8*)(t_bf + ((size_t)(b*HWP + hs*WID + wsr)*128 + 64 + c8));
            stg[j] = v;
        }
    }
    __syncthreads();

    f32x4 acc[4][4];
#pragma unroll
    for (int mi = 0; mi < 4; ++mi)
#pragma unroll
        for (int nfl = 0; nfl < 4; ++nfl) acc[mi][nfl] = (f32x4){0.f,0.f,0.f,0.f};

    const int mcol = lane & 15;
    const int koff = (lane >> 4) << 3;

#pragma unroll 1
    for (int k = 0; k < 2; ++k) {
#pragma unroll 1
        for (int tap = 0; tap < 9; ++tap) {
            const int dy = tap / 3, dx = tap - dy*3;
            const int col = mcol + dx;
            const int swz = (col & 7) << 3;
#pragma unroll
            for (int ks2 = 0; ks2 < 2; ++ks2) {
                bf16x8 Bf[4];
#pragma unroll
                for (int nfl = 0; nfl < 4; ++nfl)
                    Bf[nfl] = *(const bf16x8*)(wo2p + (((size_t)((tap*4 + k*2 + ks2)*8 + cg*4 + nfl))*64 + lane)*8);
#pragma unroll
                for (int mi = 0; mi < 4; ++mi) {
                    int mf = w*4 + mi;
                    int r_ = mf >> 1, g = mf & 1;
                    int idx = ((((r_ + dy)*34 + g*16 + col))*64 + ks2*32 + koff) ^ swz;
                    bf16x8 Af = *(const bf16x8*)(&halo[idx]);
#pragma unroll
                    for (int nfl = 0; nfl < 4; ++nfl)
                        acc[mi][nfl] = __builtin_amdgcn_mfma_f32_16x16x32_bf16(Af, Bf[nfl], acc[mi][nfl], 0, 0, 0);
                }
            }
        }
        if (k == 0) {
            __syncthreads();
#pragma unroll
            for (int j = 0; j < 11; ++j) {
                int i = cell0 + 32*j;
                if (i < 340) {
                    int cc = i % 34;
                    *(bf16x8*)(&halo[(i*64 + c8) ^ ((cc & 7) << 3)]) = stg[j];
                }
            }
            __syncthreads();
        }
    }

    float* fbuf = (float*)halo;
    const int cl0 = lane & 15;
    const int rg  = (lane >> 4) << 2;
    const int c32 = t & 31;
    const int row8 = t >> 5;
#pragma unroll 1
    for (int sp = 0; sp < 2; ++sp) {
        __syncthreads();
#pragma unroll
        for (int mi = 0; mi < 4; ++mi)
#pragma unroll
            for (int nl = 0; nl < 2; ++nl) {
                int nfl = sp*2 + nl;
                int mf = w*4 + mi;
                int pix = (mf >> 1)*32 + (mf & 1)*16 + rg;
                *(f32x4*)(fbuf + (nl*16 + cl0)*260 + pix) = acc[mi][nfl];
            }
        __syncthreads();
        {
            const int c  = cg*64 + sp*32 + c32;
            const float gt  = gate[b*CH + c];
            const float gti = 1.0f - gt;
            const float b2v = bo2[c];
            const int gbase = (b*CH + c)*HWP + (h0 + row8)*WID + w0;
            float* od = out + gbase;
#pragma unroll
            for (int q = 0; q < 4; ++q) {
                f32x4 cv0 = *(const f32x4*)(fbuf + c32*260 + row8*32 + q*8);
                f32x4 cv1 = *(const f32x4*)(fbuf + c32*260 + row8*32 + q*8 + 4);
                bf16x8 gq8 = *(const bf16x8*)(gq_bf + gbase + q*8);
                bf16x8 fc8 = *(const bf16x8*)(fc_bf + gbase + q*8);
                float vv[8];
#pragma unroll
                for (int jj = 0; jj < 4; ++jj) {
                    vv[jj]   = gt*(cv0[jj] + b2v + bf2f((ushort)gq8[jj]))   + gti*bf2f((ushort)fc8[jj]);
                    vv[4+jj] = gt*(cv1[jj] + b2v + bf2f((ushort)gq8[4+jj])) + gti*bf2f((ushort)fc8[4+jj]);
                }
                *(float4*)(od + q*8)     = (float4){vv[0],vv[1],vv[2],vv[3]};
                *(float4*)(od + q*8 + 4) = (float4){vv[4],vv[5],vv[6],vv[7]};
            }
        }
    }
}

extern "C" void kernel_launch(void* const* d_in, const int* in_sizes, int n_in,
                              void* d_out, int out_size, void* d_ws, size_t ws_size,
                              hipStream_t stream)
{
    const float* bev = (const float*)d_in[0];
    const float* snr = (const float*)d_in[1];
    const float* vr  = (const float*)d_in[2];
    const float* Wq  = (const float*)d_in[3];
    const float* bq  = (const float*)d_in[4];
    const float* Wk  = (const float*)d_in[5];
    const float* bk  = (const float*)d_in[6];
    const float* Wv  = (const float*)d_in[7];
    const float* bv  = (const float*)d_in[8];
    const float* Wo1 = (const float*)d_in[9];
    const float* bo1 = (const float*)d_in[10];
    const float* Wo2 = (const float*)d_in[11];
    const float* bo2 = (const float*)d_in[12];
    const float* Wc1 = (const float*)d_in[13];
    const float* bc1 = (const float*)d_in[14];
    const float* Wc2 = (const float*)d_in[15];
    const float* bc2 = (const float*)d_in[16];
    const float* Wg  = (const float*)d_in[17];
    const float* bg  = (const float*)d_in[18];
    const float* Wr1 = (const float*)d_in[19];
    const float* br1 = (const float*)d_in[20];
    const float* Wr2 = (const float*)d_in[21];
    const float* br2 = (const float*)d_in[22];

    char* wsb = (char*)d_ws;
    ushort* t_bf  = (ushort*)(wsb);                       // 16 MB
    ushort* gq_bf = (ushort*)(wsb + 16777216);            // 16 MB
    ushort* fc_bf = (ushort*)(wsb + 33554432);            // 16 MB
    ushort* wqp   = (ushort*)(wsb + 50331648);
    ushort* wkp   = wqp + 16384;
    ushort* wvp   = wkp + 16384;
    ushort* wo1p  = wvp + 16384;
    ushort* wc1p  = wo1p + 16384;
    ushort* wo2p  = wc1p + 4096;                          // 147,456 ushorts
    float*  gate  = (float*)(wsb + 50331648 + 434176);
    float*  relb  = gate + 512;

    float* outp   = (float*)d_out;
    float* attn_o = outp + 8388608;
    float* conf_o = outp + 8781824;

    fusion_setup<<<2, 256, 0, stream>>>(snr, vr, Wg, bg, Wr1, br1, Wr2, br2,
                                        relb, gate);
    pack_weights<<<106, 256, 0, stream>>>(Wq, Wk, Wv, Wo1, Wc1, Wo2,
                                          wqp, wkp, wvp, wo1p, wc1p, wo2p);
    fusion_attn<<<2048, 256, 0, stream>>>(bev, wqp, wkp, wvp, wo1p, wc1p,
                                          bq, bk, bv, bo1, bc1, bc2, Wc2, relb,
                                          gq_bf, t_bf, fc_bf, attn_o, conf_o);
    fusion_conv3<<<512, 256, 0, stream>>>(t_bf, gq_bf, fc_bf, wo2p, bo2, gate, outp);
}

// Round 17
// 141.251 us; speedup vs baseline: 2.4914x; 2.4914x over previous
//
#include <hip/hip_runtime.h>
#include <hip/hip_bf16.h>
#include <math.h>

// Round 27: REVERT to R25 exactly (verified best: 142.3us total, attn 116us,
// FETCH 99MB / WRITE 53MB / conflicts 131K / VGPR 68).
// R26's occupancy push (4 blocks/CU) failed doubly: (a) allocator shrank to
// 64 VGPR and spilled the 24-deep Phase-A load pipeline (~300MB scratch
// traffic); (b) the v3-5 "L2-hot" re-read was cold at 32 blocks/XCD
// (+340MB FETCH). Occupancy >3 blocks/CU now falsified from three
// directions (R12 work-split, R19 allocator hint, R26 LDS shrink): the
// 3-block/CU separate-pass structure is this kernel's constrained optimum.
// Session wins retained: Q-pass algebraic collapse (q=Wq·mean(x)), softmax
// phase elimination (raw-e + deferred normalize), upgraded bank swizzle
// (conflicts 5.1M->131K), conv3 full-line stores + channel split + single
// buffer halo, XCD swizzles, lean register discipline (biases sunk).
// B=4 N=6 C=128 H=W=128, HEADS=4 HD=32 MID=32.

#define BB   4
#define NV   6
#define CH   128
#define HGT  128
#define WID  128
#define MIDD 32
#define HWP  (HGT*WID)
#define TP   32

#define SWZ(pix) ((((pix) & 15) << 3) ^ (((pix) & 24) << 1))

typedef __attribute__((ext_vector_type(8))) short bf16x8;
typedef __attribute__((ext_vector_type(4))) float f32x4;
typedef __attribute__((ext_vector_type(2))) unsigned int u32x2;

union U8 { bf16x8 v; unsigned u[4]; };

__device__ __forceinline__ ushort f2bf(float f) {
    union { __hip_bfloat16 h; ushort u; } v;
    v.h = __float2bfloat16(f);
    return v.u;
}
__device__ __forceinline__ float bf2f(ushort u) {
    return __uint_as_float(((unsigned)u) << 16);
}
__device__ __forceinline__ unsigned cvt_pk_bf16(float lo, float hi) {
    unsigned r;
    asm("v_cvt_pk_bf16_f32 %0, %1, %2" : "=v"(r) : "v"(lo), "v"(hi));
    return r;
}

// ---------------- setup: rel_bias, gate ----------------
__global__ void fusion_setup(const float* __restrict__ snr, const float* __restrict__ vr,
                             const float* __restrict__ Wg, const float* __restrict__ bg,
                             const float* __restrict__ Wr1, const float* __restrict__ br1,
                             const float* __restrict__ Wr2, const float* __restrict__ br2,
                             float* __restrict__ relb, float* __restrict__ gate)
{
    int tid = blockIdx.x * blockDim.x + threadIdx.x;
    if (tid < BB*CH) {
        int b = tid >> 7, c = tid & 127;
        float s = snr[b] * 0.05f;
        s = fminf(fmaxf(s, -1.5f), 1.5f);
        float z = s * Wg[c] + bg[c];
        gate[tid] = 1.0f / (1.0f + __expf(-z));
    }
    if (tid < BB*NV) {
        int b = tid / NV, n = tid % NV;
        float v0 = vr[(b*NV+n)*3+0], v1 = vr[(b*NV+n)*3+1], v2 = vr[(b*NV+n)*3+2];
        float acc = br2[0];
        for (int j = 0; j < MIDD; ++j) {
            float h = Wr1[j*3+0]*v0 + Wr1[j*3+1]*v1 + Wr1[j*3+2]*v2 + br1[j];
            acc += Wr2[j] * fmaxf(h, 0.0f);
        }
        relb[tid] = acc;
    }
}

// ---------------- weight frag-packing ----------------
__global__ void pack_weights(const float* __restrict__ Wq, const float* __restrict__ Wk,
                             const float* __restrict__ Wv, const float* __restrict__ Wo1,
                             const float* __restrict__ Wc1, const float* __restrict__ Wo2,
                             ushort* __restrict__ wqp, ushort* __restrict__ wkp,
                             ushort* __restrict__ wvp, ushort* __restrict__ wo1p,
                             ushort* __restrict__ wc1p, ushort* __restrict__ wo2p)
{
    int tid = blockIdx.x * 256 + threadIdx.x;
    if (tid >= 27136) return;
    if (tid < 8192) {
        int m = tid >> 11;
        int local = tid & 2047;
        const float* src = (m == 0) ? Wq : (m == 1) ? Wk : (m == 2) ? Wv : Wo1;
        ushort* dst = (m == 0) ? wqp : (m == 1) ? wkp : (m == 2) ? wvp : wo1p;
        int ks = local >> 9, rem = local & 511;
        int nf = rem >> 6, lane = rem & 63;
        int o = nf*16 + (lane & 15);
        int i0 = ks*32 + ((lane >> 4) << 3);
        const float* s = src + o*CH + i0;
        ushort* d = dst + local*8;
#pragma unroll
        for (int j = 0; j < 8; ++j) d[j] = f2bf(s[j]);
    } else if (tid < 8704) {
        int local = tid - 8192;
        int ks = local >> 7, rem = local & 127;
        int nf = rem >> 6, lane = rem & 63;
        int o = nf*16 + (lane & 15);
        int i0 = ks*32 + ((lane >> 4) << 3);
        const float* s = Wc1 + o*CH + i0;
        ushort* d = wc1p + local*8;
#pragma unroll
        for (int j = 0; j < 8; ++j) d[j] = f2bf(s[j]);
    } else {
        int l2 = tid - 8704;
        int lane = l2 & 63;
        int rest = l2 >> 6;
        int nf = rest & 7;
        int kst = rest >> 3;
        int ks = kst & 3;
        int tap = kst >> 2;
        int co = nf*16 + (lane & 15);
        int ci0 = ks*32 + ((lane >> 4) << 3);
        ushort* d = wo2p + l2*8;
#pragma unroll
        for (int j = 0; j < 8; ++j) d[j] = f2bf(Wo2[(co*CH + ci0 + j)*9 + tap]);
    }
}

// ---------------- MFMA helpers ----------------
__device__ __forceinline__ bf16x8 ldsA(const ushort* tile, int lane, int mf, int ks) {
    int pix = mf*16 + (lane & 15);
    int idx = (pix*128 + ks*32 + ((lane >> 4) << 3)) ^ SWZ(pix);
    return *(const bf16x8*)(tile + idx);
}
__device__ __forceinline__ bf16x8 ldB(const ushort* pack, int lane, int ks, int nf, int NF) {
    return *(const bf16x8*)(pack + (((ks*NF + nf)*64) + lane)*8);
}

// ---------------- fusion_attn: per (b, 32-pix tile) ----------------
__global__ __launch_bounds__(256, 3) void fusion_attn(
    const float* __restrict__ bev,
    const ushort* __restrict__ wqp, const ushort* __restrict__ wkp,
    const ushort* __restrict__ wvp, const ushort* __restrict__ wo1p,
    const ushort* __restrict__ wc1p,
    const float* __restrict__ bq, const float* __restrict__ bk,
    const float* __restrict__ bv, const float* __restrict__ bo1,
    const float* __restrict__ bc1, const float* __restrict__ bc2,
    const float* __restrict__ Wc2, const float* __restrict__ relb,
    ushort* __restrict__ gq_bf, ushort* __restrict__ t_bf, ushort* __restrict__ fc_bf,
    float* __restrict__ attn_o, float* __restrict__ conf_o)
{
    __shared__ ushort xt[NV][TP*128];   // swizzled [pix][c] bf16; xt[0] reused for fused
    __shared__ union {
        struct {
            float scat[NV][4][TP];      // raw e per (view, head, pix)
            float dnm[4][TP];           // 1/denom per (head, pix)
            float lpart[NV][TP];
            float cfw[NV][TP];
        } s;
        ushort gqh[16*128];             // x-bar half-tile (4KB), dead before conf
    } aux;

    const int t = threadIdx.x, lane = t & 63, w = t >> 6;
    // bijective XCD swizzle: 2048 blocks = 8 XCDs x 256 contiguous tiles.
    const int vb = ((blockIdx.x & 7) << 8) | (blockIdx.x >> 3);
    const int b = vb >> 9;
    const int pix0 = (vb & 511) * TP;

    // ---- Phase A: stage 6 views -> LDS bf16 swizzled; ALL loads in flight ----
    const int pixg = (t & 3) * 8;
    const int c0   = (t >> 2) * 2;
    const float* sb = bev + (((size_t)b*NV*CH + c0)*HWP + pix0 + pixg);
    const size_t vstep = (size_t)CH*HWP;
    float gacc[16];
#pragma unroll
    for (int i = 0; i < 16; ++i) gacc[i] = 0.f;
    float4 L[NV][4];                     // 24 loads issued back-to-back (static idx)
#pragma unroll
    for (int j = 0; j < NV; ++j) {
        const float* s1 = sb + (size_t)j*vstep;
        L[j][0] = *(const float4*)(s1);
        L[j][1] = *(const float4*)(s1 + 4);
        L[j][2] = *(const float4*)(s1 + HWP);
        L[j][3] = *(const float4*)(s1 + HWP + 4);
    }
#pragma unroll
    for (int n = 0; n < NV; ++n) {
        float4 a0 = L[n][0], a1 = L[n][1], b0 = L[n][2], b1 = L[n][3];
        float r0[8] = {a0.x,a0.y,a0.z,a0.w, a1.x,a1.y,a1.z,a1.w};
        float r1[8] = {b0.x,b0.y,b0.z,b0.w, b1.x,b1.y,b1.z,b1.w};
#pragma unroll
        for (int p = 0; p < 8; ++p) {
            int pix = pixg + p;
            unsigned pk = cvt_pk_bf16(r0[p], r1[p]);
            *(unsigned*)(&xt[n][(pix*128 + c0) ^ SWZ(pix)]) = pk;
            gacc[p]   += r0[p];
            gacc[8+p] += r1[p];
        }
    }
    {
        U8 g0, g1;
#pragma unroll
        for (int p = 0; p < 4; ++p) {
            g0.u[p] = cvt_pk_bf16(gacc[2*p]   * (1.0f/6.0f), gacc[2*p+1] * (1.0f/6.0f));
            g1.u[p] = cvt_pk_bf16(gacc[8+2*p] * (1.0f/6.0f), gacc[9+2*p] * (1.0f/6.0f));
        }
        ushort* gd = gq_bf + ((size_t)(b*CH + c0)*HWP + pix0 + pixg);
        *(bf16x8*)(gd)       = g0.v;
        *(bf16x8*)(gd + HWP) = g1.v;
    }
    // x-bar half0 (pix 0-15) into gqh, swizzled [pix][c]; SWZ on pix&15 so
    // writer swizzle == reader swizzle (reader sees only lane&15).
    if ((t & 3) < 2) {
#pragma unroll
        for (int p = 0; p < 8; ++p) {
            int pix = pixg + p;
            unsigned pk = cvt_pk_bf16(gacc[p]*(1.0f/6.0f), gacc[8+p]*(1.0f/6.0f));
            *(unsigned*)(&aux.gqh[((pix & 15)*128 + c0) ^ SWZ(pix & 15)]) = pk;
        }
    }
    __syncthreads();   // B1

    const int cl0 = (lane & 15);
    const int rg  = (lane >> 4) << 2;

    // ---- Pass 1: Q = Wq · x-bar via half-tiles (16 MFMAs) ----
    f32x4 qf[2][2];   // [pix-tile mf][ch-tile nfl], rows = channel
#pragma unroll
    for (int mf = 0; mf < 2; ++mf)
#pragma unroll
        for (int nfl = 0; nfl < 2; ++nfl) qf[mf][nfl] = (f32x4){0.f,0.f,0.f,0.f};
    {
        bf16x8 xg[4];
#pragma unroll
        for (int ks = 0; ks < 4; ++ks) xg[ks] = ldsA(aux.gqh, lane, 0, ks);
#pragma unroll
        for (int nfl = 0; nfl < 2; ++nfl)
#pragma unroll
            for (int ks = 0; ks < 4; ++ks)
                qf[0][nfl] = __builtin_amdgcn_mfma_f32_16x16x32_bf16(
                    ldB(wqp, lane, ks, 2*w + nfl, 8), xg[ks], qf[0][nfl], 0, 0, 0);
    }
    __syncthreads();   // B1a: all waves done reading half0
    if ((t & 3) >= 2) {
#pragma unroll
        for (int p = 0; p < 8; ++p) {
            int pix = pixg + p;
            unsigned pk = cvt_pk_bf16(gacc[p]*(1.0f/6.0f), gacc[8+p]*(1.0f/6.0f));
            *(unsigned*)(&aux.gqh[((pix & 15)*128 + c0) ^ SWZ(pix & 15)]) = pk;
        }
    }
    __syncthreads();   // B1b: half1 visible
    {
        bf16x8 xg[4];
#pragma unroll
        for (int ks = 0; ks < 4; ++ks) xg[ks] = ldsA(aux.gqh, lane, 0, ks);
#pragma unroll
        for (int nfl = 0; nfl < 2; ++nfl)
#pragma unroll
            for (int ks = 0; ks < 4; ++ks)
                qf[1][nfl] = __builtin_amdgcn_mfma_f32_16x16x32_bf16(
                    ldB(wqp, lane, ks, 2*w + nfl, 8), xg[ks], qf[1][nfl], 0, 0, 0);
    }
    __syncthreads();   // B1c: gqh dead; aux.s may now be written

    // ---- conf for this wave's views (w, w+4 if <NV) ----
#pragma unroll
    for (int vi = 0; vi < 2; ++vi) {
        int n = w + vi*4;
        if (n < NV) {
            bf16x8 xA[2][4];
#pragma unroll
            for (int mf = 0; mf < 2; ++mf)
#pragma unroll
                for (int ks = 0; ks < 4; ++ks) xA[mf][ks] = ldsA(xt[n], lane, mf, ks);
            f32x4 cf[2][2];   // [mf][mid-tile], rows = mid channel
#pragma unroll
            for (int mf = 0; mf < 2; ++mf)
#pragma unroll
                for (int nfc = 0; nfc < 2; ++nfc) cf[mf][nfc] = (f32x4){0.f,0.f,0.f,0.f};
#pragma unroll
            for (int nfc = 0; nfc < 2; ++nfc) {
#pragma unroll
                for (int ks = 0; ks < 4; ++ks) {
                    bf16x8 bb = ldB(wc1p, lane, ks, nfc, 2);
#pragma unroll
                    for (int mf = 0; mf < 2; ++mf)
                        cf[mf][nfc] = __builtin_amdgcn_mfma_f32_16x16x32_bf16(bb, xA[mf][ks], cf[mf][nfc], 0, 0, 0);
                }
            }
            const f32x4 bc1T0 = *(const f32x4*)(bc1 + rg),  bc1T1 = *(const f32x4*)(bc1 + 16 + rg);
            const f32x4 wc2T0 = *(const f32x4*)(Wc2 + rg),  wc2T1 = *(const f32x4*)(Wc2 + 16 + rg);
#pragma unroll
            for (int mf = 0; mf < 2; ++mf) {
                float pl = 0.f;
#pragma unroll
                for (int r = 0; r < 4; ++r) {
                    pl += fmaxf(cf[mf][0][r] + bc1T0[r], 0.f) * wc2T0[r];
                    pl += fmaxf(cf[mf][1][r] + bc1T1[r], 0.f) * wc2T1[r];
                }
                pl += __shfl_xor(pl, 16, 64);
                pl += __shfl_xor(pl, 32, 64);
                if (lane < 16) aux.s.lpart[n][mf*16 + lane] = pl;
            }
        }
    }
    {
        const f32x4 bqT0 = *(const f32x4*)(bq + w*32 + rg), bqT1 = *(const f32x4*)(bq + w*32 + 16 + rg);
#pragma unroll
        for (int mf = 0; mf < 2; ++mf)
#pragma unroll
            for (int r = 0; r < 4; ++r) {
                qf[mf][0][r] = qf[mf][0][r] + bqT0[r];
                qf[mf][1][r] = qf[mf][1][r] + bqT1[r];
            }
    }

    // ---- Pass 2: K^T per view -> raw e in all lanes, denom in-register ----
    float sb2[2];
    {
        const f32x4 bkT0 = *(const f32x4*)(bk + w*32 + rg), bkT1 = *(const f32x4*)(bk + w*32 + 16 + rg);
#pragma unroll
        for (int mf = 0; mf < 2; ++mf) {
            float v = 0.f;
#pragma unroll
            for (int r = 0; r < 4; ++r) {
                v += qf[mf][0][r]*bkT0[r];
                v += qf[mf][1][r]*bkT1[r];
            }
            sb2[mf] = v;
        }
    }
    float denom[2] = {0.f, 0.f};
#pragma unroll 2
    for (int n = 0; n < NV; ++n) {
        bf16x8 xA[2][4];
#pragma unroll
        for (int mf = 0; mf < 2; ++mf)
#pragma unroll
            for (int ks = 0; ks < 4; ++ks) xA[mf][ks] = ldsA(xt[n], lane, mf, ks);
        f32x4 kf[2][2];
#pragma unroll
        for (int mf = 0; mf < 2; ++mf)
#pragma unroll
            for (int nfl = 0; nfl < 2; ++nfl) kf[mf][nfl] = (f32x4){0.f,0.f,0.f,0.f};
#pragma unroll
        for (int nfl = 0; nfl < 2; ++nfl)
#pragma unroll
            for (int ks = 0; ks < 4; ++ks) {
                bf16x8 bb = ldB(wkp, lane, ks, 2*w + nfl, 8);
#pragma unroll
                for (int mf = 0; mf < 2; ++mf)
                    kf[mf][nfl] = __builtin_amdgcn_mfma_f32_16x16x32_bf16(bb, xA[mf][ks], kf[mf][nfl], 0, 0, 0);
            }
#pragma unroll
        for (int mf = 0; mf < 2; ++mf) {
            float s = sb2[mf];
#pragma unroll
            for (int r = 0; r < 4; ++r) {
                s += qf[mf][0][r]*kf[mf][0][r];
                s += qf[mf][1][r]*kf[mf][1][r];
            }
            s += __shfl_xor(s, 16, 64);
            s += __shfl_xor(s, 32, 64);   // full channel sum in all lanes
            float e = __expf(s * 0.17677669529663687f);
            denom[mf] += e;
            if (lane < 16) aux.s.scat[n][w][mf*16 + lane] = e;   // raw, normalized at consumers
        }
    }
    const float inv0 = 1.0f/denom[0], inv1 = 1.0f/denom[1];
    if (lane < 32) aux.s.dnm[w][lane] = (lane & 16) ? inv1 : inv0;

    // ---- Pass 3: V^T per view; a = scat*inv (same-wave RAW, no barrier) ----
    f32x4 ff[2][2];
#pragma unroll
    for (int mf = 0; mf < 2; ++mf)
#pragma unroll
        for (int nfl = 0; nfl < 2; ++nfl) ff[mf][nfl] = (f32x4){0.f,0.f,0.f,0.f};
#pragma unroll 2
    for (int n = 0; n < NV; ++n) {
        bf16x8 xA[2][4];
#pragma unroll
        for (int mf = 0; mf < 2; ++mf)
#pragma unroll
            for (int ks = 0; ks < 4; ++ks) xA[mf][ks] = ldsA(xt[n], lane, mf, ks);
        f32x4 vv[2][2];
#pragma unroll
        for (int mf = 0; mf < 2; ++mf)
#pragma unroll
            for (int nfl = 0; nfl < 2; ++nfl) vv[mf][nfl] = (f32x4){0.f,0.f,0.f,0.f};
#pragma unroll
        for (int nfl = 0; nfl < 2; ++nfl)
#pragma unroll
            for (int ks = 0; ks < 4; ++ks) {
                bf16x8 bb = ldB(wvp, lane, ks, 2*w + nfl, 8);
#pragma unroll
                for (int mf = 0; mf < 2; ++mf)
                    vv[mf][nfl] = __builtin_amdgcn_mfma_f32_16x16x32_bf16(bb, xA[mf][ks], vv[mf][nfl], 0, 0, 0);
            }
        float a0 = aux.s.scat[n][w][cl0]      * inv0;
        float a1 = aux.s.scat[n][w][16 + cl0] * inv1;
#pragma unroll
        for (int r = 0; r < 4; ++r) {
            ff[0][0][r] += a0 * vv[0][0][r];
            ff[0][1][r] += a0 * vv[0][1][r];
            ff[1][0][r] += a1 * vv[1][0][r];
            ff[1][1][r] += a1 * vv[1][1][r];
        }
    }
    {
        const f32x4 bvT0 = *(const f32x4*)(bv + w*32 + rg), bvT1 = *(const f32x4*)(bv + w*32 + 16 + rg);
#pragma unroll
        for (int mf = 0; mf < 2; ++mf)
#pragma unroll
            for (int r = 0; r < 4; ++r) { ff[mf][0][r] += bvT0[r]; ff[mf][1][r] += bvT1[r]; }
    }
    __syncthreads();   // B2

    // ---- conf softmax (t<32) || attn_o mean (t<192, normalized via dnm) ----
    if (t < 32) {
        int pix = t;
        float bc2v = bc2[0];
        float lg[NV];
#pragma unroll
        for (int n = 0; n < NV; ++n)
            lg[n] = aux.s.lpart[n][pix] + bc2v + relb[b*NV + n];
        float mx = fmaxf(fmaxf(fmaxf(lg[0],lg[1]),fmaxf(lg[2],lg[3])),fmaxf(lg[4],lg[5]));
        float e[NV], sum = 0.f;
#pragma unroll
        for (int n = 0; n < NV; ++n) { e[n] = __expf(lg[n]-mx); sum += e[n]; }
        float inv = 1.0f/sum;
#pragma unroll
        for (int n = 0; n < NV; ++n) {
            float wv = e[n]*inv;
            aux.s.cfw[n][pix] = wv;
            conf_o[(b*NV + n)*HWP + pix0 + pix] = wv;
        }
    }
    if (t < 192) {
        int n = t >> 5, pix = t & 31;
        float am = 0.25f*(aux.s.scat[n][0][pix]*aux.s.dnm[0][pix] + aux.s.scat[n][1][pix]*aux.s.dnm[1][pix]
                        + aux.s.scat[n][2][pix]*aux.s.dnm[2][pix] + aux.s.scat[n][3][pix]*aux.s.dnm[3][pix]);
        attn_o[(b*NV + n)*HWP + pix0 + pix] = am;
    }
    __syncthreads();   // B3

    // ---- fc = sum_n cfw[n]*x_n -> fc_bf NCHW bf16 ----
    {
        float fcv[16];
#pragma unroll
        for (int i = 0; i < 16; ++i) fcv[i] = 0.f;
#pragma unroll
        for (int n = 0; n < NV; ++n) {
#pragma unroll
            for (int p = 0; p < 8; ++p) {
                int pix = pixg + p;
                float cwv = aux.s.cfw[n][pix];
                unsigned pk = *(const unsigned*)(&xt[n][(pix*128 + c0) ^ SWZ(pix)]);
                fcv[p]   += cwv * bf2f((ushort)(pk & 0xffffu));
                fcv[8+p] += cwv * bf2f((ushort)(pk >> 16));
            }
        }
        U8 f0, f1;
#pragma unroll
        for (int p = 0; p < 4; ++p) {
            f0.u[p] = cvt_pk_bf16(fcv[2*p],   fcv[2*p+1]);
            f1.u[p] = cvt_pk_bf16(fcv[8+2*p], fcv[9+2*p]);
        }
        ushort* fd = fc_bf + ((size_t)(b*CH + c0)*HWP + pix0 + pixg);
        *(bf16x8*)(fd)       = f0.v;
        *(bf16x8*)(fd + HWP) = f1.v;
    }
    __syncthreads();   // B4 (fc's xt[0] reads done before overwrite)

    // ---- fused frags -> xt[0] (swizzled), 4 x b64 writes ----
    {
        ushort* xt0 = &xt[0][0];
#pragma unroll
        for (int mf = 0; mf < 2; ++mf)
#pragma unroll
            for (int nfl = 0; nfl < 2; ++nfl) {
                int pix = mf*16 + cl0;
                int c   = w*32 + nfl*16 + rg;
                unsigned lo = cvt_pk_bf16(ff[mf][nfl][0], ff[mf][nfl][1]);
                unsigned hi = cvt_pk_bf16(ff[mf][nfl][2], ff[mf][nfl][3]);
                *(u32x2*)(&xt0[(pix*128 + c) ^ SWZ(pix)]) = (u32x2){lo, hi};
            }
    }
    __syncthreads();   // B5

    // ---- Phase F: t = relu(Wo1 @ fused + bo1) -> t_bf NHWC bf16 (R14 exact) ----
    {
        bf16x8 aA[2][4];
#pragma unroll
        for (int mf = 0; mf < 2; ++mf)
#pragma unroll
            for (int ks = 0; ks < 4; ++ks) aA[mf][ks] = ldsA(&xt[0][0], lane, mf, ks);
        f32x4 tf[2][2];
#pragma unroll
        for (int mf = 0; mf < 2; ++mf)
#pragma unroll
            for (int nfl = 0; nfl < 2; ++nfl) tf[mf][nfl] = (f32x4){0.f,0.f,0.f,0.f};
#pragma unroll
        for (int nfl = 0; nfl < 2; ++nfl) {
            int nf = 2*w + nfl;
#pragma unroll
            for (int ks = 0; ks < 4; ++ks) {
                bf16x8 bb = ldB(wo1p, lane, ks, nf, 8);
#pragma unroll
                for (int mf = 0; mf < 2; ++mf)
                    tf[mf][nfl] = __builtin_amdgcn_mfma_f32_16x16x32_bf16(aA[mf][ks], bb, tf[mf][nfl], 0, 0, 0);
            }
        }
        const float bov0 = bo1[w*32 + cl0], bov1 = bo1[w*32 + 16 + cl0];
#pragma unroll
        for (int mf = 0; mf < 2; ++mf)
#pragma unroll
            for (int nfl = 0; nfl < 2; ++nfl)
#pragma unroll
                for (int r = 0; r < 4; ++r) {
                    int pix = mf*16 + rg + r;
                    int c   = w*32 + nfl*16 + cl0;
                    float bo_ = nfl ? bov1 : bov0;
                    t_bf[(size_t)(b*HWP + pix0 + pix)*128 + c] = f2bf(fmaxf(tf[mf][nfl][r] + bo_, 0.f));
                }
    }
}

// ---------------- conv3x3 v3: 8x32 tiles, full-line out writes, channel-split ----------------
__global__ __launch_bounds__(256, 2) void fusion_conv3(
    const ushort* __restrict__ t_bf, const ushort* __restrict__ gq_bf,
    const ushort* __restrict__ fc_bf, const ushort* __restrict__ wo2p,
    const float* __restrict__ bo2, const float* __restrict__ gate,
    float* __restrict__ out)
{
    __shared__ ushort halo[10*34*64];   // 43520 B; reused as fbuf in epilogue

    const int t = threadIdx.x, lane = t & 63, w = t >> 6;
    // bijective XCD swizzle: 512 blocks = 8 XCDs x 64 contiguous virtual blocks
    // -> cg-pairs (vb, vb^1) sharing the same halo land on one XCD's L2.
    const int vbk = ((blockIdx.x & 7) << 6) | (blockIdx.x >> 3);
    const int cg   = vbk & 1;                 // output-channel group (64 ch)
    const int tile = (vbk >> 1) & 63;
    const int b    = vbk >> 7;
    const int h0 = (tile >> 2) * 8;           // 16 row-bands of 8
    const int w0 = (tile & 3) * 32;           // 4 col-bands of 32

    const int c8   = (t & 7) * 8;
    const int cell0 = t >> 3;

    // stage input channels 0-63 into halo (10 x 34 cells)
    for (int i = cell0; i < 340; i += 32) {
        int r = i / 34, cc = i - r*34;
        int hs = h0 - 1 + r, wsr = w0 - 1 + cc;
        bf16x8 v = (bf16x8){0,0,0,0,0,0,0,0};
        if ((unsigned)hs < (unsigned)HGT && (unsigned)wsr < (unsigned)WID)
            v = *(const bf16x8*)(t_bf + ((size_t)(b*HWP + hs*WID + wsr)*128 + c8));
        *(bf16x8*)(&halo[(i*64 + c8) ^ ((cc & 7) << 3)]) = v;
    }
    // prefetch input channels 64-127 into registers
    bf16x8 stg[11];
#pragma unroll
    for (int j = 0; j < 11; ++j) {
        int i = cell0 + 32*j;
        if (i < 340) {
            int r = i / 34, cc = i - r*34;
            int hs = h0 - 1 + r, wsr = w0 - 1 + cc;
            bf16x8 v = (bf16x8){0,0,0,0,0,0,0,0};
            if ((unsigned)hs < (unsigned)HGT && (unsigned)wsr < (unsigned)WID)
                v = *(const bf16x8*)(t_bf + ((size_t)(b*HWP + hs*WID + wsr)*128 + 64 + c8));
            stg[j] = v;
        }
    }
    __syncthreads();

    f32x4 acc[4][4];
#pragma unroll
    for (int mi = 0; mi < 4; ++mi)
#pragma unroll
        for (int nfl = 0; nfl < 4; ++nfl) acc[mi][nfl] = (f32x4){0.f,0.f,0.f,0.f};

    const int mcol = lane & 15;
    const int koff = (lane >> 4) << 3;

#pragma unroll 1
    for (int k = 0; k < 2; ++k) {
#pragma unroll 1
        for (int tap = 0; tap < 9; ++tap) {
            const int dy = tap / 3, dx = tap - dy*3;
            const int col = mcol + dx;
            const int swz = (col & 7) << 3;
#pragma unroll
            for (int ks2 = 0; ks2 < 2; ++ks2) {
                bf16x8 Bf[4];
#pragma unroll
                for (int nfl = 0; nfl < 4; ++nfl)
                    Bf[nfl] = *(const bf16x8*)(wo2p + (((size_t)((tap*4 + k*2 + ks2)*8 + cg*4 + nfl))*64 + lane)*8);
#pragma unroll
                for (int mi = 0; mi < 4; ++mi) {
                    int mf = w*4 + mi;
                    int r_ = mf >> 1, g = mf & 1;           // tile row, col-halfgroup
                    int idx = ((((r_ + dy)*34 + g*16 + col))*64 + ks2*32 + koff) ^ swz;
                    bf16x8 Af = *(const bf16x8*)(&halo[idx]);
#pragma unroll
                    for (int nfl = 0; nfl < 4; ++nfl)
                        acc[mi][nfl] = __builtin_amdgcn_mfma_f32_16x16x32_bf16(Af, Bf[nfl], acc[mi][nfl], 0, 0, 0);
                }
            }
        }
        if (k == 0) {
            __syncthreads();   // all k=0 reads done before overwrite
#pragma unroll
            for (int j = 0; j < 11; ++j) {
                int i = cell0 + 32*j;
                if (i < 340) {
                    int cc = i % 34;
                    *(bf16x8*)(&halo[(i*64 + c8) ^ ((cc & 7) << 3)]) = stg[j];
                }
            }
            __syncthreads();   // halo now holds input channels 64-127
        }
    }

    // epilogue: 2 sub-passes of 32 output channels via fbuf (32 x 260 floats)
    float* fbuf = (float*)halo;
    const int cl0 = lane & 15;
    const int rg  = (lane >> 4) << 2;
    const int c32 = t & 31;
    const int row8 = t >> 5;            // 0..7 (8 tile rows)
#pragma unroll 1
    for (int sp = 0; sp < 2; ++sp) {
        __syncthreads();   // prior halo/fbuf reads done
#pragma unroll
        for (int mi = 0; mi < 4; ++mi)
#pragma unroll
            for (int nl = 0; nl < 2; ++nl) {
                int nfl = sp*2 + nl;
                int mf = w*4 + mi;
                int pix = (mf >> 1)*32 + (mf & 1)*16 + rg;   // row*32 + colgroup*16
                *(f32x4*)(fbuf + (nl*16 + cl0)*260 + pix) = acc[mi][nfl];
            }
        __syncthreads();
        {
            const int c  = cg*64 + sp*32 + c32;
            const float gt  = gate[b*CH + c];
            const float gti = 1.0f - gt;
            const float b2v = bo2[c];
            const int gbase = (b*CH + c)*HWP + (h0 + row8)*WID + w0;
            float* od = out + gbase;
#pragma unroll
            for (int q = 0; q < 4; ++q) {
                f32x4 cv0 = *(const f32x4*)(fbuf + c32*260 + row8*32 + q*8);
                f32x4 cv1 = *(const f32x4*)(fbuf + c32*260 + row8*32 + q*8 + 4);
                bf16x8 gq8 = *(const bf16x8*)(gq_bf + gbase + q*8);
                bf16x8 fc8 = *(const bf16x8*)(fc_bf + gbase + q*8);
                float vv[8];
#pragma unroll
                for (int jj = 0; jj < 4; ++jj) {
                    vv[jj]   = gt*(cv0[jj] + b2v + bf2f((ushort)gq8[jj]))   + gti*bf2f((ushort)fc8[jj]);
                    vv[4+jj] = gt*(cv1[jj] + b2v + bf2f((ushort)gq8[4+jj])) + gti*bf2f((ushort)fc8[4+jj]);
                }
                *(float4*)(od + q*8)     = (float4){vv[0],vv[1],vv[2],vv[3]};
                *(float4*)(od + q*8 + 4) = (float4){vv[4],vv[5],vv[6],vv[7]};
            }
        }
    }
}

extern "C" void kernel_launch(void* const* d_in, const int* in_sizes, int n_in,
                              void* d_out, int out_size, void* d_ws, size_t ws_size,
                              hipStream_t stream)
{
    const float* bev = (const float*)d_in[0];
    const float* snr = (const float*)d_in[1];
    const float* vr  = (const float*)d_in[2];
    const float* Wq  = (const float*)d_in[3];
    const float* bq  = (const float*)d_in[4];
    const float* Wk  = (const float*)d_in[5];
    const float* bk  = (const float*)d_in[6];
    const float* Wv  = (const float*)d_in[7];
    const float* bv  = (const float*)d_in[8];
    const float* Wo1 = (const float*)d_in[9];
    const float* bo1 = (const float*)d_in[10];
    const float* Wo2 = (const float*)d_in[11];
    const float* bo2 = (const float*)d_in[12];
    const float* Wc1 = (const float*)d_in[13];
    const float* bc1 = (const float*)d_in[14];
    const float* Wc2 = (const float*)d_in[15];
    const float* bc2 = (const float*)d_in[16];
    const float* Wg  = (const float*)d_in[17];
    const float* bg  = (const float*)d_in[18];
    const float* Wr1 = (const float*)d_in[19];
    const float* br1 = (const float*)d_in[20];
    const float* Wr2 = (const float*)d_in[21];
    const float* br2 = (const float*)d_in[22];

    char* wsb = (char*)d_ws;
    ushort* t_bf  = (ushort*)(wsb);                       // 16 MB
    ushort* gq_bf = (ushort*)(wsb + 16777216);            // 16 MB
    ushort* fc_bf = (ushort*)(wsb + 33554432);            // 16 MB
    ushort* wqp   = (ushort*)(wsb + 50331648);
    ushort* wkp   = wqp + 16384;
    ushort* wvp   = wkp + 16384;
    ushort* wo1p  = wvp + 16384;
    ushort* wc1p  = wo1p + 16384;
    ushort* wo2p  = wc1p + 4096;                          // 147,456 ushorts
    float*  gate  = (float*)(wsb + 50331648 + 434176);
    float*  relb  = gate + 512;

    float* outp   = (float*)d_out;
    float* attn_o = outp + 8388608;
    float* conf_o = outp + 8781824;

    fusion_setup<<<2, 256, 0, stream>>>(snr, vr, Wg, bg, Wr1, br1, Wr2, br2,
                                        relb, gate);
    pack_weights<<<106, 256, 0, stream>>>(Wq, Wk, Wv, Wo1, Wc1, Wo2,
                                          wqp, wkp, wvp, wo1p, wc1p, wo2p);
    fusion_attn<<<2048, 256, 0, stream>>>(bev, wqp, wkp, wvp, wo1p, wc1p,
                                          bq, bk, bv, bo1, bc1, bc2, Wc2, relb,
                                          gq_bf, t_bf, fc_bf, attn_o, conf_o);
    fusion_conv3<<<512, 256, 0, stream>>>(t_bf, gq_bf, fc_bf, wo2p, bo2, gate, outp);
}